// Round 2
// baseline (750.079 us; speedup 1.0000x reference)
//
#include <hip/hip_runtime.h>

#define NCAP 10     // capsule classes c
#define NB   256    // batch b
#define NN   1152   // route nodes n
#define KI   8      // input dim i
#define NO   16     // output dim o
#define NT   384    // threads per block (6 waves)
#define NPT  3      // n per thread: 384*3 = 1152
#define NW   6      // waves per block
#define NITER 3

__global__ __launch_bounds__(NT) void capsule_kernel(
    const float* __restrict__ x,    // [256,1152,8]
    const float* __restrict__ w,    // [10,1152,8,16]
    float* __restrict__ out)        // [10,256,16]
{
    __shared__ float s_red[NW];            // per-wave lsum
    __shared__ float s_spc[NW][NO][NO+1];  // per-wave per-column sp partials (padded)
    __shared__ float s_v[NO];              // broadcast of v

    const int t    = threadIdx.x;
    const int wave = t >> 6;
    const int lane = t & 63;

    // XCD-aware swizzle: 2560 % 8 == 0 -> bijective; same-c blocks cluster
    // on one XCD so W[c] (576 KB) stays L2-resident.
    const int bid = blockIdx.x;
    const int swz = (bid & 7) * (NCAP * NB / 8) + (bid >> 3);
    const int c = swz / NB;
    const int b = swz % NB;

    // ---- priors: prior[k][o] = x[b,n,:] . W[c,n,:,o],  n = t + 384k ----
    float prior[NPT][NO];
    #pragma unroll
    for (int k = 0; k < NPT; ++k) {
        const int n = t + NT * k;
        const float4* xv = reinterpret_cast<const float4*>(x + ((size_t)b * NN + n) * KI);
        float4 x0 = xv[0], x1 = xv[1];
        float xi[KI] = {x0.x, x0.y, x0.z, x0.w, x1.x, x1.y, x1.z, x1.w};
        const float4* wv = reinterpret_cast<const float4*>(w + ((size_t)c * NN + n) * (KI * NO));
        #pragma unroll
        for (int o = 0; o < NO; ++o) prior[k][o] = 0.f;
        #pragma unroll
        for (int i = 0; i < KI; ++i) {
            #pragma unroll
            for (int j = 0; j < 4; ++j) {
                float4 wq = wv[i * 4 + j];
                prior[k][4*j+0] = fmaf(xi[i], wq.x, prior[k][4*j+0]);
                prior[k][4*j+1] = fmaf(xi[i], wq.y, prior[k][4*j+1]);
                prior[k][4*j+2] = fmaf(xi[i], wq.z, prior[k][4*j+2]);
                prior[k][4*j+3] = fmaf(xi[i], wq.w, prior[k][4*j+3]);
            }
        }
    }

    float logit[NPT] = {0.f, 0.f, 0.f};

    for (int iter = 0; iter < NITER; ++iter) {
        // ---- fused exp + lsum + weighted-sum partials (no max-sub needed:
        // |logit| <= ~25, exp fine in fp32, mathematically identical) ----
        float lsum = 0.f;
        float sp[NO];
        #pragma unroll
        for (int o = 0; o < NO; ++o) sp[o] = 0.f;
        #pragma unroll
        for (int k = 0; k < NPT; ++k) {
            float e = __expf(logit[k]);
            lsum += e;
            #pragma unroll
            for (int o = 0; o < NO; ++o) sp[o] = fmaf(e, prior[k][o], sp[o]);
        }

        // lsum: full wave butterfly, lane0 writes per-wave partial
        lsum += __shfl_xor(lsum, 1);
        lsum += __shfl_xor(lsum, 2);
        lsum += __shfl_xor(lsum, 4);
        lsum += __shfl_xor(lsum, 8);
        lsum += __shfl_xor(lsum, 16);
        lsum += __shfl_xor(lsum, 32);
        if (lane == 0) s_red[wave] = lsum;

        // sp: 2-stage column reduce (lanes {l, l^16, l^32, l^48} summed),
        // lanes 0-15 dump their 16-vector of column sums to padded LDS
        #pragma unroll
        for (int o = 0; o < NO; ++o) {
            float s = sp[o];
            s += __shfl_xor(s, 16);
            s += __shfl_xor(s, 32);
            if (lane < NO) s_spc[wave][lane][o] = s;
        }
        __syncthreads();

        // ---- finalize on 16 threads: sum partials, softmax-normalize, squash ----
        if (t < NO) {
            float acc = 0.f, lt = 0.f;
            #pragma unroll
            for (int w2 = 0; w2 < NW; ++w2) {
                lt += s_red[w2];
                #pragma unroll
                for (int col = 0; col < NO; ++col) acc += s_spc[w2][col][t];
            }
            float s_o = acc / lt;
            float sq = s_o * s_o;
            sq += __shfl_xor(sq, 1);
            sq += __shfl_xor(sq, 2);
            sq += __shfl_xor(sq, 4);
            sq += __shfl_xor(sq, 8);
            float scale = sq / ((1.f + sq) * sqrtf(sq));
            float vo = s_o * scale;
            s_v[t] = vo;
            if (iter == NITER - 1) out[((size_t)c * NB + b) * NO + t] = vo;
        }
        __syncthreads();

        // ---- logit update: thread-private, zero communication ----
        if (iter < NITER - 1) {
            float vv[NO];
            #pragma unroll
            for (int o = 0; o < NO; ++o) vv[o] = s_v[o];
            #pragma unroll
            for (int k = 0; k < NPT; ++k) {
                float d = 0.f;
                #pragma unroll
                for (int o = 0; o < NO; ++o) d = fmaf(prior[k][o], vv[o], d);
                logit[k] += d;
            }
        }
    }
}

extern "C" void kernel_launch(void* const* d_in, const int* in_sizes, int n_in,
                              void* d_out, int out_size, void* d_ws, size_t ws_size,
                              hipStream_t stream) {
    const float* x = (const float*)d_in[0];
    const float* w = (const float*)d_in[1];
    float* out = (float*)d_out;
    capsule_kernel<<<dim3(NCAP * NB), dim3(NT), 0, stream>>>(x, w, out);
}